// Round 11
// baseline (211.767 us; speedup 1.0000x reference)
//
#include <hip/hip_runtime.h>
#include <hip/hip_bf16.h>
#include <stdint.h>

typedef __attribute__((ext_vector_type(8))) _Float16 f16x8;
typedef __attribute__((ext_vector_type(4))) _Float16 f16x4;
typedef __attribute__((ext_vector_type(4))) float f32x4;

static constexpr int BATCH = 2;
static constexpr int SEQ = 2048;
static constexpr int EMB = 1024;
static constexpr int NH = 16;
static constexpr int HD_ = 64;

#define AS1 __attribute__((address_space(1)))
#define AS3 __attribute__((address_space(3)))

__device__ __forceinline__ void gload_lds16(const void* g, void* l) {
  __builtin_amdgcn_global_load_lds((const AS1 uint32_t*)g, (AS3 uint32_t*)l, 16, 0, 0);
}

__device__ __forceinline__ f32x4 mfma16(f16x8 a, f16x8 b, f32x4 c) {
  return __builtin_amdgcn_mfma_f32_16x16x32_f16(a, b, c, 0, 0, 0);
}

// swizzled 16B-block read from a 128B-row LDS tile: byte ^= (row&7)<<4
__device__ __forceinline__ f16x8 swzread(const _Float16* base, int row, int blk) {
  return *(const f16x8*)((const char*)base + row * 128 +
                         ((blk * 16) ^ ((row & 7) << 4)));
}

// ---------------- convert f32 -> f16 hi/lo split (hi+lo ~ 22 mantissa bits) ----------------
__global__ __launch_bounds__(256) void k_convert_split(const float* __restrict__ in,
                                                       _Float16* __restrict__ oh,
                                                       _Float16* __restrict__ ol,
                                                       int n4) {
  int idx = blockIdx.x * 256 + threadIdx.x;
  if (idx >= n4) return;
  float4 v = reinterpret_cast<const float4*>(in)[idx];
  const float* f = reinterpret_cast<const float*>(&v);
  _Float16 h[4], l[4];
#pragma unroll
  for (int i = 0; i < 4; ++i) {
    h[i] = (_Float16)f[i];
    l[i] = (_Float16)(f[i] - (float)h[i]);
  }
  reinterpret_cast<uint2*>(oh)[idx] = *reinterpret_cast<uint2*>(h);
  reinterpret_cast<uint2*>(ol)[idx] = *reinterpret_cast<uint2*>(l);
}

// ---------------- transpose+convert to f16: in[R][C] f32 -> out[perm(C)][R] ----------------
// PERM 1: Wqkv column permutation to [q(1024) | k(1024) | v(1024)]
template <int PERM>
__global__ __launch_bounds__(256) void k_transpose(const float* __restrict__ in,
                                                   _Float16* __restrict__ out, int R,
                                                   int C) {
  __shared__ float tile[32][33];
  const int t = threadIdx.x;
  const int tr = t >> 5, tc = t & 31;
  const int r0 = blockIdx.y * 32, c0 = blockIdx.x * 32;
#pragma unroll
  for (int rr = 0; rr < 32; rr += 8)
    tile[tr + rr][tc] = in[(size_t)(r0 + tr + rr) * C + c0 + tc];
  __syncthreads();
#pragma unroll
  for (int rr = 0; rr < 32; rr += 8) {
    const int c = c0 + tr + rr;
    int d = c;
    if constexpr (PERM) {
      const int h = c / 192, r = c - h * 192;
      d = (r < 64) ? h * 64 + r
                   : (r < 128 ? 1024 + h * 64 + (r - 64) : 2048 + h * 64 + (r - 128));
    }
    out[(size_t)d * R + r0 + tc] = (_Float16)tile[tc][tr + rr];
  }
}

// ---------------- fused QKV GEMM: A(hi/lo f16)[4096][1024] x Bt f16[3072][1024]^T ----------
// cols [0,1024)=q (2-MFMA split), [1024,2048)=k (2-MFMA split), [2048,3072)=v (1-MFMA)
// epilogue scatter: q_s f16 (x 8*log2e), k_s f16, v_t f16 transposed (f16x4 stores)
__global__ __launch_bounds__(256) void k_gemm_qkv(
    const _Float16* __restrict__ Ah, const _Float16* __restrict__ Al,
    const _Float16* __restrict__ Bt, const float* __restrict__ bias,
    _Float16* __restrict__ oq, _Float16* __restrict__ ok,
    _Float16* __restrict__ ov) {
  constexpr int K = EMB;
  __shared__ _Float16 AsH[2][128 * 32];
  __shared__ _Float16 AsL[2][128 * 32];
  __shared__ _Float16 Bs[2][128 * 32];
  const int t = threadIdx.x;
  const int l = t & 63, w = t >> 6;
  const int lr = l & 15, lg = l >> 4;
  const int wr = w >> 1, wc = w & 1;
  const int m0 = blockIdx.y * 128, n0 = blockIdx.x * 128;
  const bool splitb = (n0 < 2048);  // block-uniform

  auto stage = [&](int buf, int k0) {
#pragma unroll
    for (int j = 0; j < 2; ++j) {
      const int c = t + 256 * j;
      const int row = c >> 2, cb = c & 3;
      const size_t ga = (size_t)(m0 + row) * K + k0 + cb * 8;
      const size_t gb = (size_t)(n0 + row) * K + k0 + cb * 8;
      gload_lds16(Ah + ga, &AsH[buf][c * 8]);
      gload_lds16(Bt + gb, &Bs[buf][c * 8]);
      if (splitb) gload_lds16(Al + ga, &AsL[buf][c * 8]);
    }
  };

  f32x4 acc[4][4];
#pragma unroll
  for (int m = 0; m < 4; ++m)
#pragma unroll
    for (int n = 0; n < 4; ++n) acc[m][n] = f32x4{0.f, 0.f, 0.f, 0.f};

  stage(0, 0);
  const int NT = K / 32;
  int cur = 0;
  for (int kt = 0; kt < NT; ++kt) {
    __syncthreads();
    if (kt + 1 < NT) stage(cur ^ 1, (kt + 1) * 32);
    f16x8 afh[4], afl[4], bf[4];
#pragma unroll
    for (int m = 0; m < 4; ++m) {
      const int off = (wr * 64 + m * 16 + lr) * 32 + lg * 8;
      afh[m] = *(const f16x8*)&AsH[cur][off];
      if (splitb) afl[m] = *(const f16x8*)&AsL[cur][off];
    }
#pragma unroll
    for (int n = 0; n < 4; ++n)
      bf[n] = *(const f16x8*)&Bs[cur][(wc * 64 + n * 16 + lr) * 32 + lg * 8];
#pragma unroll
    for (int m = 0; m < 4; ++m)
#pragma unroll
      for (int n = 0; n < 4; ++n) {
        acc[m][n] = mfma16(afh[m], bf[n], acc[m][n]);
        if (splitb) acc[m][n] = mfma16(afl[m], bf[n], acc[m][n]);
      }
    cur ^= 1;
  }

  const int sec = n0 >> 10;  // 0=q 1=k 2=v (block-uniform)
#pragma unroll
  for (int m = 0; m < 4; ++m) {
#pragma unroll
    for (int n = 0; n < 4; ++n) {
      const int col = n0 + wc * 64 + n * 16 + lr;
      const int cc = col & 1023;
      const int h = cc >> 6, r = cc & 63;
      const float bv = bias[h * 192 + sec * 64 + r];
      const int row0 = m0 + wr * 64 + m * 16 + lg * 4;
      const int b = row0 >> 11, s0 = row0 & (SEQ - 1);
      if (sec == 2) {  // V^T: i -> s consecutive, 4-aligned -> one 8B store
        f16x4 vv;
#pragma unroll
        for (int i = 0; i < 4; ++i) vv[i] = (_Float16)(acc[m][n][i] + bv);
        *(f16x4*)&ov[(((size_t)b * NH + h) * HD_ + r) * SEQ + s0] = vv;
      } else {
#pragma unroll
        for (int i = 0; i < 4; ++i) {
          const float v = acc[m][n][i] + bv;
          const size_t dst = (((size_t)b * NH + h) * SEQ + s0 + i) * HD_ + r;
          if (sec == 0)
            oq[dst] = (_Float16)(v * 11.5415603f);  // 8*log2(e) folded
          else
            ok[dst] = (_Float16)v;
        }
      }
    }
  }
}

// ---------------- proj GEMM: a_o f16 x Wproj_t f16^T -> f32 + bias ----------------
__global__ __launch_bounds__(256) void k_gemm_proj(const _Float16* __restrict__ A,
                                                   const _Float16* __restrict__ Bt,
                                                   const float* __restrict__ bias,
                                                   float* __restrict__ of) {
  constexpr int K = EMB, N = EMB;
  __shared__ _Float16 As[2][128 * 32];
  __shared__ _Float16 Bs[2][128 * 32];
  const int t = threadIdx.x;
  const int l = t & 63, w = t >> 6;
  const int lr = l & 15, lg = l >> 4;
  const int wr = w >> 1, wc = w & 1;
  const int m0 = blockIdx.y * 128, n0 = blockIdx.x * 128;

  auto stage = [&](int buf, int k0) {
#pragma unroll
    for (int j = 0; j < 2; ++j) {
      const int c = t + 256 * j;
      const int row = c >> 2, cb = c & 3;
      gload_lds16(A + (size_t)(m0 + row) * K + k0 + cb * 8, &As[buf][c * 8]);
      gload_lds16(Bt + (size_t)(n0 + row) * K + k0 + cb * 8, &Bs[buf][c * 8]);
    }
  };

  f32x4 acc[4][4];
#pragma unroll
  for (int m = 0; m < 4; ++m)
#pragma unroll
    for (int n = 0; n < 4; ++n) acc[m][n] = f32x4{0.f, 0.f, 0.f, 0.f};

  stage(0, 0);
  const int NT = K / 32;
  int cur = 0;
  for (int kt = 0; kt < NT; ++kt) {
    __syncthreads();
    if (kt + 1 < NT) stage(cur ^ 1, (kt + 1) * 32);
    f16x8 af[4], bf[4];
#pragma unroll
    for (int m = 0; m < 4; ++m)
      af[m] = *(const f16x8*)&As[cur][(wr * 64 + m * 16 + lr) * 32 + lg * 8];
#pragma unroll
    for (int n = 0; n < 4; ++n)
      bf[n] = *(const f16x8*)&Bs[cur][(wc * 64 + n * 16 + lr) * 32 + lg * 8];
#pragma unroll
    for (int m = 0; m < 4; ++m)
#pragma unroll
      for (int n = 0; n < 4; ++n) acc[m][n] = mfma16(af[m], bf[n], acc[m][n]);
    cur ^= 1;
  }

#pragma unroll
  for (int m = 0; m < 4; ++m)
#pragma unroll
    for (int n = 0; n < 4; ++n)
#pragma unroll
      for (int i = 0; i < 4; ++i) {
        const int row = m0 + wr * 64 + m * 16 + lg * 4 + i;
        const int col = n0 + wc * 64 + n * 16 + lr;
        of[(size_t)row * N + col] = acc[m][n][i] + bias[col];
      }
}

// ---------------- flash attention, KV-split, 2 q-tiles per wave ----------------
// Each wave: 32 q-rows (tiles A,B). K frags read once feed both QK^T; V frags
// read once feed both PV (interleaved). P double-buffered per wave in LDS.
// Negligible-tile skip: __all(tm < mr-24) -> tile contributes < 2^-24 rel.
// LDS 64KB -> 2 blocks/CU; grid 512 = (bh, 256 q-rows, kv-half).
__global__ __launch_bounds__(512, 4) void k_attn(
    const _Float16* __restrict__ qs, const _Float16* __restrict__ ks,
    const _Float16* __restrict__ vt, _Float16* __restrict__ op,
    float* __restrict__ marr, float* __restrict__ larr) {
  __shared__ _Float16 Kt[2][64][64];     // [buf][kv][d]   swizzled rows (128B)
  __shared__ _Float16 Vt[2][64][64];     // [buf][d][kv]   swizzled rows
  __shared__ _Float16 Pl[8][2][16][64];  // per-wave, per-qtile P, swizzled rows
  const int t = threadIdx.x;
  const int l = t & 63, w = t >> 6;      // w in [0,8)
  const int lr = l & 15, lg = l >> 4;
  // XCD-grouping: id&7 -> XCD; per XCD: 4 heads x 8 q-blocks x 2 halves
  const int id = blockIdx.x;
  const int xc = id & 7, m_ = id >> 3;   // m_ in [0,64)
  const int kvh = m_ & 1;
  const int bh = xc + 8 * (m_ >> 4);
  const int qb = ((m_ >> 1) & 7) * 256 + w * 32;  // wave: rows qb..qb+31
  const int kvbase = kvh * (SEQ / 2);

  // Q fragments for both tiles (B-operand: n=q=lr, k=d)
  const size_t qoffA = ((size_t)bh * SEQ + qb + lr) * HD_;
  const size_t qoffB = qoffA + (size_t)16 * HD_;
  const f16x8 qfA0 = *(const f16x8*)(qs + qoffA + lg * 8);
  const f16x8 qfA1 = *(const f16x8*)(qs + qoffA + 32 + lg * 8);
  const f16x8 qfB0 = *(const f16x8*)(qs + qoffB + lg * 8);
  const f16x8 qfB1 = *(const f16x8*)(qs + qoffB + 32 + lg * 8);

  const _Float16* kbase = ks + (size_t)bh * SEQ * HD_;
  const _Float16* vbase = vt + (size_t)bh * HD_ * SEQ;

  // async staging: 512 threads cover the 64x64 tile in one pass each for K,V.
  // LDS dest linear (DMA rule); global SOURCE block pre-swizzled (T21).
  const int srow = t >> 3, scb = t & 7;  // srow in [0,64)
  auto stage = [&](const int buf, const int kv0) {
    gload_lds16(kbase + (size_t)(kv0 + srow) * HD_ + (scb ^ (srow & 7)) * 8,
                &Kt[buf][srow][scb * 8]);
    gload_lds16(vbase + (size_t)srow * SEQ + kv0 + (scb ^ (srow & 7)) * 8,
                &Vt[buf][srow][scb * 8]);
  };

  stage(0, kvbase);

  float mrA = -1e30f, lsumA = 0.f, mrB = -1e30f, lsumB = 0.f;
  f32x4 oaccA[4], oaccB[4];
#pragma unroll
  for (int n = 0; n < 4; ++n) {
    oaccA[n] = f32x4{0.f, 0.f, 0.f, 0.f};
    oaccB[n] = f32x4{0.f, 0.f, 0.f, 0.f};
  }

  const int NT = SEQ / 128;  // 16 tiles per half
  for (int it = 0; it < NT; ++it) {
    const int cur = it & 1;
    __syncthreads();  // drains vmcnt: buf[cur] DMA complete; prev reads done
    if (it + 1 < NT) stage(cur ^ 1, kvbase + (it + 1) * 64);

    // K fragments once, feed both Q tiles
    f16x8 kf0[4], kf1[4];
#pragma unroll
    for (int t4 = 0; t4 < 4; ++t4) {
      const int r = t4 * 16 + lr;
      kf0[t4] = swzread(&Kt[cur][0][0], r, lg);
      kf1[t4] = swzread(&Kt[cur][0][0], r, lg + 4);
    }

    // ---- tile A: QK^T, softmax, P ----
    f32x4 saA[4];
    __builtin_amdgcn_s_setprio(1);
#pragma unroll
    for (int t4 = 0; t4 < 4; ++t4) {
      f32x4 s = mfma16(kf0[t4], qfA0, f32x4{0.f, 0.f, 0.f, 0.f});
      saA[t4] = mfma16(kf1[t4], qfA1, s);
    }
    __builtin_amdgcn_s_setprio(0);

    float tmA = fmaxf(fmaxf(fmaxf(saA[0][0], saA[0][1]), fmaxf(saA[0][2], saA[0][3])),
                      fmaxf(fmaxf(saA[1][0], saA[1][1]), fmaxf(saA[1][2], saA[1][3])));
    tmA = fmaxf(tmA,
                fmaxf(fmaxf(fmaxf(saA[2][0], saA[2][1]), fmaxf(saA[2][2], saA[2][3])),
                      fmaxf(fmaxf(saA[3][0], saA[3][1]), fmaxf(saA[3][2], saA[3][3]))));
    tmA = fmaxf(tmA, __shfl_xor(tmA, 16));
    tmA = fmaxf(tmA, __shfl_xor(tmA, 32));
    const bool skipA = __all(tmA < mrA - 24.0f);  // tile < 2^-24 relative
    if (!skipA) {
      if (__any(tmA > mrA + 8.0f)) {  // wave-uniform rescale (defer-max THR=8)
        const float nm = fmaxf(mrA, tmA);
        const float corr = exp2f(mrA - nm);
        mrA = nm;
        lsumA *= corr;
        float cb4[4];
#pragma unroll
        for (int i = 0; i < 4; ++i)
          cb4[i] = __shfl(corr, (l & 48) + ((l >> 4) << 2) + i);
#pragma unroll
        for (int n = 0; n < 4; ++n)
#pragma unroll
          for (int i = 0; i < 4; ++i) oaccA[n][i] *= cb4[i];
      }
      float ts = 0.f;
      char* plA = (char*)&Pl[w][0][0][0];
#pragma unroll
      for (int t4 = 0; t4 < 4; ++t4) {
        f16x4 pp;
#pragma unroll
        for (int i = 0; i < 4; ++i) {
          const float p = exp2f(saA[t4][i] - mrA);
          ts += p;
          pp[i] = (_Float16)p;
        }
        *(f16x4*)(plA + lr * 128 + ((t4 * 32 + lg * 8) ^ ((lr & 7) << 4))) = pp;
      }
      ts += __shfl_xor(ts, 16);
      ts += __shfl_xor(ts, 32);
      lsumA += ts;
    }

    // ---- tile B: QK^T, softmax, P ----
    f32x4 saB[4];
    __builtin_amdgcn_s_setprio(1);
#pragma unroll
    for (int t4 = 0; t4 < 4; ++t4) {
      f32x4 s = mfma16(kf0[t4], qfB0, f32x4{0.f, 0.f, 0.f, 0.f});
      saB[t4] = mfma16(kf1[t4], qfB1, s);
    }
    __builtin_amdgcn_s_setprio(0);

    float tmB = fmaxf(fmaxf(fmaxf(saB[0][0], saB[0][1]), fmaxf(saB[0][2], saB[0][3])),
                      fmaxf(fmaxf(saB[1][0], saB[1][1]), fmaxf(saB[1][2], saB[1][3])));
    tmB = fmaxf(tmB,
                fmaxf(fmaxf(fmaxf(saB[2][0], saB[2][1]), fmaxf(saB[2][2], saB[2][3])),
                      fmaxf(fmaxf(saB[3][0], saB[3][1]), fmaxf(saB[3][2], saB[3][3]))));
    tmB = fmaxf(tmB, __shfl_xor(tmB, 16));
    tmB = fmaxf(tmB, __shfl_xor(tmB, 32));
    const bool skipB = __all(tmB < mrB - 24.0f);
    if (!skipB) {
      if (__any(tmB > mrB + 8.0f)) {
        const float nm = fmaxf(mrB, tmB);
        const float corr = exp2f(mrB - nm);
        mrB = nm;
        lsumB *= corr;
        float cb4[4];
#pragma unroll
        for (int i = 0; i < 4; ++i)
          cb4[i] = __shfl(corr, (l & 48) + ((l >> 4) << 2) + i);
#pragma unroll
        for (int n = 0; n < 4; ++n)
#pragma unroll
          for (int i = 0; i < 4; ++i) oaccB[n][i] *= cb4[i];
      }
      float ts = 0.f;
      char* plB = (char*)&Pl[w][1][0][0];
#pragma unroll
      for (int t4 = 0; t4 < 4; ++t4) {
        f16x4 pp;
#pragma unroll
        for (int i = 0; i < 4; ++i) {
          const float p = exp2f(saB[t4][i] - mrB);
          ts += p;
          pp[i] = (_Float16)p;
        }
        *(f16x4*)(plB + lr * 128 + ((t4 * 32 + lg * 8) ^ ((lr & 7) << 4))) = pp;
      }
      ts += __shfl_xor(ts, 16);
      ts += __shfl_xor(ts, 32);
      lsumB += ts;
    }

    // ---- PV for both tiles: V fragments read once ----
    if (!(skipA && skipB)) {
      f16x8 aA0, aA1, aB0, aB1;
      if (!skipA) {
        aA0 = swzread(&Pl[w][0][0][0], lr, lg);
        aA1 = swzread(&Pl[w][0][0][0], lr, lg + 4);
      }
      if (!skipB) {
        aB0 = swzread(&Pl[w][1][0][0], lr, lg);
        aB1 = swzread(&Pl[w][1][0][0], lr, lg + 4);
      }
      __builtin_amdgcn_s_setprio(1);
#pragma unroll
      for (int n = 0; n < 4; ++n) {
        const int d = n * 16 + lr;
        const f16x8 bv0 = swzread(&Vt[cur][0][0], d, lg);
        const f16x8 bv1 = swzread(&Vt[cur][0][0], d, lg + 4);
        if (!skipA) {
          oaccA[n] = mfma16(aA0, bv0, oaccA[n]);
          oaccA[n] = mfma16(aA1, bv1, oaccA[n]);
        }
        if (!skipB) {
          oaccB[n] = mfma16(aB0, bv0, oaccB[n]);
          oaccB[n] = mfma16(aB1, bv1, oaccB[n]);
        }
      }
      __builtin_amdgcn_s_setprio(0);
    }
  }

  // epilogue: per-row (m, lsum) for both tiles, partial O stores
  const size_t mlbase = ((size_t)kvh * 32 + bh) * SEQ + qb;
  if (l < 16) {
    marr[mlbase + l] = mrA;
    larr[mlbase + l] = lsumA;
    marr[mlbase + 16 + l] = mrB;
    larr[mlbase + 16 + l] = lsumB;
  }
  _Float16* opb = op + (size_t)kvh * BATCH * SEQ * EMB;
  const int b = bh >> 4, h = bh & 15;
#pragma unroll
  for (int n = 0; n < 4; ++n)
#pragma unroll
    for (int i = 0; i < 4; ++i) {
      const int rowA = qb + ((l >> 4) << 2) + i;
      opb[((size_t)b * SEQ + rowA) * EMB + h * HD_ + n * 16 + lr] =
          (_Float16)oaccA[n][i];
      opb[((size_t)b * SEQ + rowA + 16) * EMB + h * HD_ + n * 16 + lr] =
          (_Float16)oaccB[n][i];
    }
}

// ---------------- combine the two KV-halves ----------------
__global__ __launch_bounds__(256) void k_combine(const _Float16* __restrict__ op,
                                                 const float* __restrict__ marr,
                                                 const float* __restrict__ larr,
                                                 _Float16* __restrict__ ao) {
  const int idx = blockIdx.x * 256 + threadIdx.x;  // [0, B*S*E/8)
  const int e8 = idx & 127;                        // EMB/8 = 128
  const size_t rs = (size_t)(idx >> 7);            // b*SEQ + s
  const int h = e8 >> 3;
  const int b = (int)(rs >> 11);
  const size_t s = rs & (SEQ - 1);
  const size_t mi = ((size_t)b * NH + h) * SEQ + s;
  const float m1 = marr[mi], l1 = larr[mi];
  const float m2 = marr[(size_t)32 * SEQ + mi], l2 = larr[(size_t)32 * SEQ + mi];
  const float mx = fmaxf(m1, m2);
  const float w1 = exp2f(m1 - mx), w2 = exp2f(m2 - mx);
  const float inv = 1.0f / (l1 * w1 + l2 * w2);
  const f16x8 o1 = ((const f16x8*)op)[idx];
  const f16x8 o2 = ((const f16x8*)op)[idx + (BATCH * SEQ * EMB / 8)];
  f16x8 r;
#pragma unroll
  for (int j = 0; j < 8; ++j)
    r[j] = (_Float16)(((float)o1[j] * w1 + (float)o2[j] * w2) * inv);
  ((f16x8*)ao)[idx] = r;
}

extern "C" void kernel_launch(void* const* d_in, const int* in_sizes, int n_in,
                              void* d_out, int out_size, void* d_ws, size_t ws_size,
                              hipStream_t stream) {
  const float* query = (const float*)d_in[0];
  const float* Wqkv = (const float*)d_in[3];
  const float* bqkv = (const float*)d_in[4];
  const float* Wproj = (const float*)d_in[5];
  const float* bproj = (const float*)d_in[6];
  float* out = (float*)d_out;

  char* ws = (char*)d_ws;
  const size_t MB = 1024 * 1024;
  _Float16* q_hi    = (_Float16*)(ws + 0);         // 8MB; dead after QKV GEMM
  _Float16* q_lo    = (_Float16*)(ws + 8 * MB);    // 8MB; dead after QKV GEMM
  _Float16* Wqkv_t  = (_Float16*)(ws + 16 * MB);   // 6MB f16 (rows: q|k|v)
  _Float16* q_s     = (_Float16*)(ws + 24 * MB);   // 8MB [32][2048][64]
  _Float16* k_s     = (_Float16*)(ws + 32 * MB);   // 8MB
  _Float16* v_t     = (_Float16*)(ws + 40 * MB);   // 8MB [32][64][2048]
  _Float16* op      = (_Float16*)(ws + 0);         // 16MB partials (alias q_hi+q_lo)
  _Float16* Wproj_t = (_Float16*)(ws + 48 * MB);   // 2MB
  float*    marr    = (float*)(ws + 50 * MB);      // 512KB [2][32][2048]
  float*    larr    = (float*)(ws + 50 * MB + 512 * 1024);  // 512KB
  _Float16* a_o     = (_Float16*)(ws + 51 * MB);   // 8MB

  const int M = BATCH * SEQ;  // 4096
  k_convert_split<<<(M * EMB / 4 + 255) / 256, 256, 0, stream>>>(query, q_hi, q_lo,
                                                                 M * EMB / 4);
  k_transpose<1><<<dim3(3 * EMB / 32, EMB / 32), 256, 0, stream>>>(Wqkv, Wqkv_t, EMB,
                                                                   3 * EMB);
  k_gemm_qkv<<<dim3(24, M / 128), 256, 0, stream>>>(q_hi, q_lo, Wqkv_t, bqkv, q_s, k_s,
                                                    v_t);
  k_transpose<0><<<dim3(EMB / 32, EMB / 32), 256, 0, stream>>>(Wproj, Wproj_t, EMB, EMB);
  k_attn<<<dim3(512), 512, 0, stream>>>(q_s, k_s, v_t, op, marr, larr);
  k_combine<<<dim3(BATCH * SEQ * EMB / 8 / 256), 256, 0, stream>>>(op, marr, larr, a_o);
  k_gemm_proj<<<dim3(EMB / 128, M / 128), 256, 0, stream>>>(a_o, Wproj_t, bproj, out);
}

// Round 12
// 167.564 us; speedup vs baseline: 1.2638x; 1.2638x over previous
//
#include <hip/hip_runtime.h>
#include <hip/hip_bf16.h>
#include <stdint.h>

typedef __attribute__((ext_vector_type(8))) _Float16 f16x8;
typedef __attribute__((ext_vector_type(4))) _Float16 f16x4;
typedef __attribute__((ext_vector_type(2))) _Float16 f16x2;
typedef __attribute__((ext_vector_type(4))) float f32x4;

static constexpr int BATCH = 2;
static constexpr int SEQ = 2048;
static constexpr int EMB = 1024;
static constexpr int NH = 16;
static constexpr int HD_ = 64;

#define AS1 __attribute__((address_space(1)))
#define AS3 __attribute__((address_space(3)))

__device__ __forceinline__ void gload_lds16(const void* g, void* l) {
  __builtin_amdgcn_global_load_lds((const AS1 uint32_t*)g, (AS3 uint32_t*)l, 16, 0, 0);
}

__device__ __forceinline__ f32x4 mfma16(f16x8 a, f16x8 b, f32x4 c) {
  return __builtin_amdgcn_mfma_f32_16x16x32_f16(a, b, c, 0, 0, 0);
}

// pack two f32 -> 2x f16 (RTZ) as our f16x2 type
__device__ __forceinline__ f16x2 pk16(float a, float b) {
  auto r = __builtin_amdgcn_cvt_pkrtz(a, b);  // __fp16 ext_vector(2)
  return __builtin_bit_cast(f16x2, r);
}

// swizzled 16B-block read from a 128B-row LDS tile: byte ^= (row&7)<<4
__device__ __forceinline__ f16x8 swzread(const _Float16* base, int row, int blk) {
  return *(const f16x8*)((const char*)base + row * 128 +
                         ((blk * 16) ^ ((row & 7) << 4)));
}

// ---------------- convert f32 -> f16 hi/lo split (hi+lo ~ 22 mantissa bits) ----------------
__global__ __launch_bounds__(256) void k_convert_split(const float* __restrict__ in,
                                                       _Float16* __restrict__ oh,
                                                       _Float16* __restrict__ ol,
                                                       int n4) {
  int idx = blockIdx.x * 256 + threadIdx.x;
  if (idx >= n4) return;
  float4 v = reinterpret_cast<const float4*>(in)[idx];
  const float* f = reinterpret_cast<const float*>(&v);
  _Float16 h[4], l[4];
#pragma unroll
  for (int i = 0; i < 4; ++i) {
    h[i] = (_Float16)f[i];
    l[i] = (_Float16)(f[i] - (float)h[i]);
  }
  reinterpret_cast<uint2*>(oh)[idx] = *reinterpret_cast<uint2*>(h);
  reinterpret_cast<uint2*>(ol)[idx] = *reinterpret_cast<uint2*>(l);
}

// ---------------- transpose+convert to f16: in[R][C] f32 -> out[perm(C)][R] ----------------
// PERM 1: Wqkv column permutation to [q(1024) | k(1024) | v(1024)]
template <int PERM>
__global__ __launch_bounds__(256) void k_transpose(const float* __restrict__ in,
                                                   _Float16* __restrict__ out, int R,
                                                   int C) {
  __shared__ float tile[32][33];
  const int t = threadIdx.x;
  const int tr = t >> 5, tc = t & 31;
  const int r0 = blockIdx.y * 32, c0 = blockIdx.x * 32;
#pragma unroll
  for (int rr = 0; rr < 32; rr += 8)
    tile[tr + rr][tc] = in[(size_t)(r0 + tr + rr) * C + c0 + tc];
  __syncthreads();
#pragma unroll
  for (int rr = 0; rr < 32; rr += 8) {
    const int c = c0 + tr + rr;
    int d = c;
    if constexpr (PERM) {
      const int h = c / 192, r = c - h * 192;
      d = (r < 64) ? h * 64 + r
                   : (r < 128 ? 1024 + h * 64 + (r - 64) : 2048 + h * 64 + (r - 128));
    }
    out[(size_t)d * R + r0 + tc] = (_Float16)tile[tc][tr + rr];
  }
}

// ---------------- fused QKV GEMM: A(hi/lo f16)[4096][1024] x Bt f16[3072][1024]^T ----------
// cols [0,1024)=q (2-MFMA split), [1024,2048)=k (2-MFMA split), [2048,3072)=v (1-MFMA)
// epilogue scatter: q_s f16 (x 8*log2e), k_s f16, v_t f16 transposed (f16x4 stores)
__global__ __launch_bounds__(256) void k_gemm_qkv(
    const _Float16* __restrict__ Ah, const _Float16* __restrict__ Al,
    const _Float16* __restrict__ Bt, const float* __restrict__ bias,
    _Float16* __restrict__ oq, _Float16* __restrict__ ok,
    _Float16* __restrict__ ov) {
  constexpr int K = EMB;
  __shared__ _Float16 AsH[2][128 * 32];
  __shared__ _Float16 AsL[2][128 * 32];
  __shared__ _Float16 Bs[2][128 * 32];
  const int t = threadIdx.x;
  const int l = t & 63, w = t >> 6;
  const int lr = l & 15, lg = l >> 4;
  const int wr = w >> 1, wc = w & 1;
  const int m0 = blockIdx.y * 128, n0 = blockIdx.x * 128;
  const bool splitb = (n0 < 2048);  // block-uniform

  auto stage = [&](int buf, int k0) {
#pragma unroll
    for (int j = 0; j < 2; ++j) {
      const int c = t + 256 * j;
      const int row = c >> 2, cb = c & 3;
      const size_t ga = (size_t)(m0 + row) * K + k0 + cb * 8;
      const size_t gb = (size_t)(n0 + row) * K + k0 + cb * 8;
      gload_lds16(Ah + ga, &AsH[buf][c * 8]);
      gload_lds16(Bt + gb, &Bs[buf][c * 8]);
      if (splitb) gload_lds16(Al + ga, &AsL[buf][c * 8]);
    }
  };

  f32x4 acc[4][4];
#pragma unroll
  for (int m = 0; m < 4; ++m)
#pragma unroll
    for (int n = 0; n < 4; ++n) acc[m][n] = f32x4{0.f, 0.f, 0.f, 0.f};

  stage(0, 0);
  const int NT = K / 32;
  int cur = 0;
  for (int kt = 0; kt < NT; ++kt) {
    __syncthreads();
    if (kt + 1 < NT) stage(cur ^ 1, (kt + 1) * 32);
    f16x8 afh[4], afl[4], bf[4];
#pragma unroll
    for (int m = 0; m < 4; ++m) {
      const int off = (wr * 64 + m * 16 + lr) * 32 + lg * 8;
      afh[m] = *(const f16x8*)&AsH[cur][off];
      if (splitb) afl[m] = *(const f16x8*)&AsL[cur][off];
    }
#pragma unroll
    for (int n = 0; n < 4; ++n)
      bf[n] = *(const f16x8*)&Bs[cur][(wc * 64 + n * 16 + lr) * 32 + lg * 8];
#pragma unroll
    for (int m = 0; m < 4; ++m)
#pragma unroll
      for (int n = 0; n < 4; ++n) {
        acc[m][n] = mfma16(afh[m], bf[n], acc[m][n]);
        if (splitb) acc[m][n] = mfma16(afl[m], bf[n], acc[m][n]);
      }
    cur ^= 1;
  }

  const int sec = n0 >> 10;  // 0=q 1=k 2=v (block-uniform)
#pragma unroll
  for (int m = 0; m < 4; ++m) {
#pragma unroll
    for (int n = 0; n < 4; ++n) {
      const int col = n0 + wc * 64 + n * 16 + lr;
      const int cc = col & 1023;
      const int h = cc >> 6, r = cc & 63;
      const float bv = bias[h * 192 + sec * 64 + r];
      const int row0 = m0 + wr * 64 + m * 16 + lg * 4;
      const int b = row0 >> 11, s0 = row0 & (SEQ - 1);
      if (sec == 2) {  // V^T: i -> s consecutive, 4-aligned -> one 8B store
        f16x4 vv;
#pragma unroll
        for (int i = 0; i < 4; ++i) vv[i] = (_Float16)(acc[m][n][i] + bv);
        *(f16x4*)&ov[(((size_t)b * NH + h) * HD_ + r) * SEQ + s0] = vv;
      } else {
#pragma unroll
        for (int i = 0; i < 4; ++i) {
          const float v = acc[m][n][i] + bv;
          const size_t dst = (((size_t)b * NH + h) * SEQ + s0 + i) * HD_ + r;
          if (sec == 0)
            oq[dst] = (_Float16)(v * 11.5415603f);  // 8*log2(e) folded
          else
            ok[dst] = (_Float16)v;
        }
      }
    }
  }
}

// ---------------- proj GEMM: a_o f16 x Wproj_t f16^T -> f32 + bias ----------------
__global__ __launch_bounds__(256) void k_gemm_proj(const _Float16* __restrict__ A,
                                                   const _Float16* __restrict__ Bt,
                                                   const float* __restrict__ bias,
                                                   float* __restrict__ of) {
  constexpr int K = EMB, N = EMB;
  __shared__ _Float16 As[2][128 * 32];
  __shared__ _Float16 Bs[2][128 * 32];
  const int t = threadIdx.x;
  const int l = t & 63, w = t >> 6;
  const int lr = l & 15, lg = l >> 4;
  const int wr = w >> 1, wc = w & 1;
  const int m0 = blockIdx.y * 128, n0 = blockIdx.x * 128;

  auto stage = [&](int buf, int k0) {
#pragma unroll
    for (int j = 0; j < 2; ++j) {
      const int c = t + 256 * j;
      const int row = c >> 2, cb = c & 3;
      gload_lds16(A + (size_t)(m0 + row) * K + k0 + cb * 8, &As[buf][c * 8]);
      gload_lds16(Bt + (size_t)(n0 + row) * K + k0 + cb * 8, &Bs[buf][c * 8]);
    }
  };

  f32x4 acc[4][4];
#pragma unroll
  for (int m = 0; m < 4; ++m)
#pragma unroll
    for (int n = 0; n < 4; ++n) acc[m][n] = f32x4{0.f, 0.f, 0.f, 0.f};

  stage(0, 0);
  const int NT = K / 32;
  int cur = 0;
  for (int kt = 0; kt < NT; ++kt) {
    __syncthreads();
    if (kt + 1 < NT) stage(cur ^ 1, (kt + 1) * 32);
    f16x8 af[4], bf[4];
#pragma unroll
    for (int m = 0; m < 4; ++m)
      af[m] = *(const f16x8*)&As[cur][(wr * 64 + m * 16 + lr) * 32 + lg * 8];
#pragma unroll
    for (int n = 0; n < 4; ++n)
      bf[n] = *(const f16x8*)&Bs[cur][(wc * 64 + n * 16 + lr) * 32 + lg * 8];
#pragma unroll
    for (int m = 0; m < 4; ++m)
#pragma unroll
      for (int n = 0; n < 4; ++n) acc[m][n] = mfma16(af[m], bf[n], acc[m][n]);
    cur ^= 1;
  }

#pragma unroll
  for (int m = 0; m < 4; ++m)
#pragma unroll
    for (int n = 0; n < 4; ++n)
#pragma unroll
      for (int i = 0; i < 4; ++i) {
        const int row = m0 + wr * 64 + m * 16 + lg * 4 + i;
        const int col = n0 + wc * 64 + n * 16 + lr;
        of[(size_t)row * N + col] = acc[m][n][i] + bias[col];
      }
}

// ---------------- flash attention, KV-split (R10 geometry) + R7 VALU-cut body ------
// grid 1024 = (bh, 128 q-rows, kv-half); 512 threads; 48KB LDS.
// unroll-2 compile-time buf; mr folded into MFMA C-init; cvt_pkrtz P-pack;
// negligible-tile skip; defer-max THR=8 (base-2). Emits unnormalized partial O
// (f16) + per-row (m, lsum); combine kernel merges halves.
__global__ __launch_bounds__(512) void k_attn(
    const _Float16* __restrict__ qs, const _Float16* __restrict__ ks,
    const _Float16* __restrict__ vt, _Float16* __restrict__ op,
    float* __restrict__ marr, float* __restrict__ larr) {
  __shared__ _Float16 Kt[2][64][64];   // [buf][kv][d]   swizzled rows (128B)
  __shared__ _Float16 Vt[2][64][64];   // [buf][d][kv]   swizzled rows
  __shared__ _Float16 Pl[8][16][64];   // per-wave P [q][kv], swizzled rows
  const int t = threadIdx.x;
  const int l = t & 63, w = t >> 6;          // w in [0,8)
  const int lr = l & 15, lg = l >> 4;
  // XCD-grouping: id&7 -> XCD; per XCD: 4 heads x 16 q-blocks x 2 halves
  const int id = blockIdx.x;
  const int xc = id & 7, m_ = id >> 3;       // m_ in [0,128)
  const int kvh = m_ & 1;
  const int bh = xc + 8 * (m_ >> 5);
  const int qb = ((m_ >> 1) & 15) * 128 + w * 16;
  const int kvbase = kvh * (SEQ / 2);

  // Q fragments (B-operand: n=q=lr, k=d)
  const size_t qoff = ((size_t)bh * SEQ + qb + lr) * HD_;
  const f16x8 qf0 = *(const f16x8*)(qs + qoff + lg * 8);
  const f16x8 qf1 = *(const f16x8*)(qs + qoff + 32 + lg * 8);

  const _Float16* kbase = ks + (size_t)bh * SEQ * HD_;
  const _Float16* vbase = vt + (size_t)bh * HD_ * SEQ;

  // async staging: 512 threads cover the 64x64 tile in one pass each for K,V.
  // LDS dest linear (DMA rule); global SOURCE block pre-swizzled (T21).
  const int srow = t >> 3, scb = t & 7;      // srow in [0,64)
  auto stage = [&](const int buf, const int kv0) {
    gload_lds16(kbase + (size_t)(kv0 + srow) * HD_ + (scb ^ (srow & 7)) * 8,
                &Kt[buf][srow][scb * 8]);
    gload_lds16(vbase + (size_t)srow * SEQ + kv0 + (scb ^ (srow & 7)) * 8,
                &Vt[buf][srow][scb * 8]);
  };

  stage(0, kvbase);

  float mr = 0.f, lsum = 0.f;  // running max (base-2, clamped >=0), denom
  f32x4 oacc[4];
#pragma unroll
  for (int n = 0; n < 4; ++n) oacc[n] = f32x4{0.f, 0.f, 0.f, 0.f};

  char* plbase = (char*)&Pl[w][0][0];
  const int NT = SEQ / 128;  // 16 tiles per half

  auto body = [&](const int cur, const int it) {
    __syncthreads();  // drains vmcnt: buf[cur] DMA complete; prev reads done
    if (it + 1 < NT) stage(cur ^ 1, kvbase + (it + 1) * 64);

    // S_rel^T = K Q^T - mr (mr folded into C-init; lane: kv=16t4+4lg+i, q=lr)
    const float nmr = -mr;
    f32x4 sa[4];
    __builtin_amdgcn_s_setprio(1);
#pragma unroll
    for (int t4 = 0; t4 < 4; ++t4) {
      const int r = t4 * 16 + lr;
      const f16x8 kf0 = swzread(&Kt[cur][0][0], r, lg);
      const f16x8 kf1 = swzread(&Kt[cur][0][0], r, lg + 4);
      f32x4 s = mfma16(kf0, qf0, f32x4{nmr, nmr, nmr, nmr});
      sa[t4] = mfma16(kf1, qf1, s);
    }
    __builtin_amdgcn_s_setprio(0);

    // tile max (relative to mr)
    float t01 = fmaxf(fmaxf(sa[0][0], sa[0][1]), fmaxf(sa[0][2], sa[0][3]));
    float t23 = fmaxf(fmaxf(sa[1][0], sa[1][1]), fmaxf(sa[1][2], sa[1][3]));
    float t45 = fmaxf(fmaxf(sa[2][0], sa[2][1]), fmaxf(sa[2][2], sa[2][3]));
    float t67 = fmaxf(fmaxf(sa[3][0], sa[3][1]), fmaxf(sa[3][2], sa[3][3]));
    float tm = fmaxf(fmaxf(t01, t23), fmaxf(t45, t67));
    tm = fmaxf(tm, __shfl_xor(tm, 16));
    tm = fmaxf(tm, __shfl_xor(tm, 32));

    // whole tile negligible vs running max: contributes < 2^-24 relative
    if (__all(tm < -24.0f)) return;

    float ts = 0.f;
    auto emitP = [&](const float d) {
#pragma unroll
      for (int t4 = 0; t4 < 4; ++t4) {
        const float p0 = exp2f(sa[t4][0] - d);
        const float p1 = exp2f(sa[t4][1] - d);
        const float p2 = exp2f(sa[t4][2] - d);
        const float p3 = exp2f(sa[t4][3] - d);
        ts += (p0 + p1) + (p2 + p3);
        const f16x2 lo2 = pk16(p0, p1);
        const f16x2 hi2 = pk16(p2, p3);
        f16x4 pp;
        pp[0] = lo2[0]; pp[1] = lo2[1]; pp[2] = hi2[0]; pp[3] = hi2[1];
        *(f16x4*)(plbase + lr * 128 + ((t4 * 32 + lg * 8) ^ ((lr & 7) << 4))) = pp;
      }
    };

    if (__any(tm > 8.0f)) {  // rescale (rare after warmup, defer-max THR=8)
      const float nm = fmaxf(tm, 0.f);  // per-lane relative new max
      const float corr = exp2f(-nm);
      mr += nm;
      lsum *= corr;
      float cb4[4];
#pragma unroll
      for (int i = 0; i < 4; ++i)
        cb4[i] = __shfl(corr, (l & 48) + ((l >> 4) << 2) + i);
#pragma unroll
      for (int n = 0; n < 4; ++n)
#pragma unroll
        for (int i = 0; i < 4; ++i) oacc[n][i] *= cb4[i];
      emitP(nm);
    } else {
      emitP(0.0f);  // constant-folds: no subtract in common path
    }

    ts += __shfl_xor(ts, 16);
    ts += __shfl_xor(ts, 32);
    lsum += ts;

    // O += P V (A=P[q][kv], B=V^T[d][kv])
    const f16x8 aP0 = swzread(&Pl[w][0][0], lr, lg);
    const f16x8 aP1 = swzread(&Pl[w][0][0], lr, lg + 4);
    __builtin_amdgcn_s_setprio(1);
#pragma unroll
    for (int n = 0; n < 4; ++n) {
      const int d = n * 16 + lr;
      const f16x8 bv0 = swzread(&Vt[cur][0][0], d, lg);
      const f16x8 bv1 = swzread(&Vt[cur][0][0], d, lg + 4);
      oacc[n] = mfma16(aP0, bv0, oacc[n]);
      oacc[n] = mfma16(aP1, bv1, oacc[n]);
    }
    __builtin_amdgcn_s_setprio(0);
  };

  // unroll-2: buf index compile-time -> LDS addresses loop-invariant
  for (int it = 0; it < NT; it += 2) {
    body(0, it);
    body(1, it + 1);
  }

  // epilogue: per-row (m, lsum) — lanes 0-15 hold rows lr=l
  const size_t mlbase = ((size_t)kvh * 32 + bh) * SEQ + qb;
  if (l < 16) {
    marr[mlbase + l] = mr;
    larr[mlbase + l] = lsum;
  }
  // store unnormalized partial O as f16
  _Float16* opb = op + (size_t)kvh * BATCH * SEQ * EMB;
  const int b = bh >> 4, h = bh & 15;
#pragma unroll
  for (int n = 0; n < 4; ++n)
#pragma unroll
    for (int i = 0; i < 4; ++i) {
      const int row = qb + ((l >> 4) << 2) + i;
      opb[((size_t)b * SEQ + row) * EMB + h * HD_ + n * 16 + lr] =
          (_Float16)oacc[n][i];
    }
}

// ---------------- combine the two KV-halves ----------------
// exact for any per-half anchor m_i: l_i*2^{m_i} = sum 2^S
__global__ __launch_bounds__(256) void k_combine(const _Float16* __restrict__ op,
                                                 const float* __restrict__ marr,
                                                 const float* __restrict__ larr,
                                                 _Float16* __restrict__ ao) {
  const int idx = blockIdx.x * 256 + threadIdx.x;  // [0, B*S*E/8)
  const int e8 = idx & 127;                        // EMB/8 = 128
  const size_t rs = (size_t)(idx >> 7);            // b*SEQ + s
  const int h = e8 >> 3;
  const int b = (int)(rs >> 11);
  const size_t s = rs & (SEQ - 1);
  const size_t mi = ((size_t)b * NH + h) * SEQ + s;
  const float m1 = marr[mi], l1 = larr[mi];
  const float m2 = marr[(size_t)32 * SEQ + mi], l2 = larr[(size_t)32 * SEQ + mi];
  const float mx = fmaxf(m1, m2);
  const float w1 = exp2f(m1 - mx), w2 = exp2f(m2 - mx);
  const float inv = 1.0f / (l1 * w1 + l2 * w2);
  const f16x8 o1 = ((const f16x8*)op)[idx];
  const f16x8 o2 = ((const f16x8*)op)[idx + (BATCH * SEQ * EMB / 8)];
  f16x8 r;
#pragma unroll
  for (int j = 0; j < 8; ++j)
    r[j] = (_Float16)(((float)o1[j] * w1 + (float)o2[j] * w2) * inv);
  ((f16x8*)ao)[idx] = r;
}

extern "C" void kernel_launch(void* const* d_in, const int* in_sizes, int n_in,
                              void* d_out, int out_size, void* d_ws, size_t ws_size,
                              hipStream_t stream) {
  const float* query = (const float*)d_in[0];
  const float* Wqkv = (const float*)d_in[3];
  const float* bqkv = (const float*)d_in[4];
  const float* Wproj = (const float*)d_in[5];
  const float* bproj = (const float*)d_in[6];
  float* out = (float*)d_out;

  char* ws = (char*)d_ws;
  const size_t MB = 1024 * 1024;
  _Float16* q_hi    = (_Float16*)(ws + 0);         // 8MB; dead after QKV GEMM
  _Float16* q_lo    = (_Float16*)(ws + 8 * MB);    // 8MB; dead after QKV GEMM
  _Float16* Wqkv_t  = (_Float16*)(ws + 16 * MB);   // 6MB f16 (rows: q|k|v)
  _Float16* q_s     = (_Float16*)(ws + 24 * MB);   // 8MB [32][2048][64]
  _Float16* k_s     = (_Float16*)(ws + 32 * MB);   // 8MB
  _Float16* v_t     = (_Float16*)(ws + 40 * MB);   // 8MB [32][64][2048]
  _Float16* op      = (_Float16*)(ws + 0);         // 16MB partials (alias q_hi+q_lo)
  _Float16* Wproj_t = (_Float16*)(ws + 48 * MB);   // 2MB
  float*    marr    = (float*)(ws + 50 * MB);      // 512KB [2][32][2048]
  float*    larr    = (float*)(ws + 50 * MB + 512 * 1024);  // 512KB
  _Float16* a_o     = (_Float16*)(ws + 51 * MB);   // 8MB

  const int M = BATCH * SEQ;  // 4096
  k_convert_split<<<(M * EMB / 4 + 255) / 256, 256, 0, stream>>>(query, q_hi, q_lo,
                                                                 M * EMB / 4);
  k_transpose<1><<<dim3(3 * EMB / 32, EMB / 32), 256, 0, stream>>>(Wqkv, Wqkv_t, EMB,
                                                                   3 * EMB);
  k_gemm_qkv<<<dim3(24, M / 128), 256, 0, stream>>>(q_hi, q_lo, Wqkv_t, bqkv, q_s, k_s,
                                                    v_t);
  k_transpose<0><<<dim3(EMB / 32, EMB / 32), 256, 0, stream>>>(Wproj, Wproj_t, EMB, EMB);
  k_attn<<<dim3(1024), 512, 0, stream>>>(q_s, k_s, v_t, op, marr, larr);
  k_combine<<<dim3(BATCH * SEQ * EMB / 8 / 256), 256, 0, stream>>>(op, marr, larr, a_o);
  k_gemm_proj<<<dim3(EMB / 128, M / 128), 256, 0, stream>>>(a_o, Wproj_t, bproj, out);
}

// Round 13
// 156.232 us; speedup vs baseline: 1.3555x; 1.0725x over previous
//
#include <hip/hip_runtime.h>
#include <hip/hip_bf16.h>
#include <stdint.h>

typedef __attribute__((ext_vector_type(8))) _Float16 f16x8;
typedef __attribute__((ext_vector_type(4))) _Float16 f16x4;
typedef __attribute__((ext_vector_type(4))) float f32x4;

static constexpr int BATCH = 2;
static constexpr int SEQ = 2048;
static constexpr int EMB = 1024;
static constexpr int NH = 16;
static constexpr int HD_ = 64;

#define AS1 __attribute__((address_space(1)))
#define AS3 __attribute__((address_space(3)))

__device__ __forceinline__ void gload_lds16(const void* g, void* l) {
  __builtin_amdgcn_global_load_lds((const AS1 uint32_t*)g, (AS3 uint32_t*)l, 16, 0, 0);
}

__device__ __forceinline__ f32x4 mfma16(f16x8 a, f16x8 b, f32x4 c) {
  return __builtin_amdgcn_mfma_f32_16x16x32_f16(a, b, c, 0, 0, 0);
}

// swizzled 16B-block read from a 128B-row LDS tile: byte ^= (row&7)<<4
__device__ __forceinline__ f16x8 swzread(const _Float16* base, int row, int blk) {
  return *(const f16x8*)((const char*)base + row * 128 +
                         ((blk * 16) ^ ((row & 7) << 4)));
}

// ---------------- convert f32 -> f16 ----------------
__global__ __launch_bounds__(256) void k_convert(const float* __restrict__ in,
                                                 _Float16* __restrict__ oh, int n4) {
  int idx = blockIdx.x * 256 + threadIdx.x;
  if (idx >= n4) return;
  float4 v = reinterpret_cast<const float4*>(in)[idx];
  const float* f = reinterpret_cast<const float*>(&v);
  _Float16 h[4];
#pragma unroll
  for (int i = 0; i < 4; ++i) h[i] = (_Float16)f[i];
  reinterpret_cast<uint2*>(oh)[idx] = *reinterpret_cast<uint2*>(h);
}

// ---------------- transpose+convert to f16: in[R][C] f32 -> out[perm(C)][R] ----------------
// PERM 1: Wqkv column permutation to [q(1024) | k(1024) | v(1024)]
template <int PERM>
__global__ __launch_bounds__(256) void k_transpose(const float* __restrict__ in,
                                                   _Float16* __restrict__ out, int R,
                                                   int C) {
  __shared__ float tile[32][33];
  const int t = threadIdx.x;
  const int tr = t >> 5, tc = t & 31;
  const int r0 = blockIdx.y * 32, c0 = blockIdx.x * 32;
#pragma unroll
  for (int rr = 0; rr < 32; rr += 8)
    tile[tr + rr][tc] = in[(size_t)(r0 + tr + rr) * C + c0 + tc];
  __syncthreads();
#pragma unroll
  for (int rr = 0; rr < 32; rr += 8) {
    const int c = c0 + tr + rr;
    int d = c;
    if constexpr (PERM) {
      const int h = c / 192, r = c - h * 192;
      d = (r < 64) ? h * 64 + r
                   : (r < 128 ? 1024 + h * 64 + (r - 64) : 2048 + h * 64 + (r - 128));
    }
    out[(size_t)d * R + r0 + tc] = (_Float16)tile[tc][tr + rr];
  }
}

// ---------------- QKV GEMM: A f16[4096][1024] x Bt f16[3072][1024]^T, 1 MFMA ---------
// epilogue scatter: q_s f16 (x 8*log2e), k_s f16, v_t f16 transposed (f16x4 stores)
__global__ __launch_bounds__(256) void k_gemm_qkv(const _Float16* __restrict__ A,
                                                  const _Float16* __restrict__ Bt,
                                                  const float* __restrict__ bias,
                                                  _Float16* __restrict__ oq,
                                                  _Float16* __restrict__ ok,
                                                  _Float16* __restrict__ ov) {
  constexpr int K = EMB;
  __shared__ _Float16 As[2][128 * 32];
  __shared__ _Float16 Bs[2][128 * 32];
  const int t = threadIdx.x;
  const int l = t & 63, w = t >> 6;
  const int lr = l & 15, lg = l >> 4;
  const int wr = w >> 1, wc = w & 1;
  const int m0 = blockIdx.y * 128, n0 = blockIdx.x * 128;

  auto stage = [&](int buf, int k0) {
#pragma unroll
    for (int j = 0; j < 2; ++j) {
      const int c = t + 256 * j;
      const int row = c >> 2, cb = c & 3;
      gload_lds16(A + (size_t)(m0 + row) * K + k0 + cb * 8, &As[buf][c * 8]);
      gload_lds16(Bt + (size_t)(n0 + row) * K + k0 + cb * 8, &Bs[buf][c * 8]);
    }
  };

  f32x4 acc[4][4];
#pragma unroll
  for (int m = 0; m < 4; ++m)
#pragma unroll
    for (int n = 0; n < 4; ++n) acc[m][n] = f32x4{0.f, 0.f, 0.f, 0.f};

  stage(0, 0);
  const int NT = K / 32;
  int cur = 0;
  for (int kt = 0; kt < NT; ++kt) {
    __syncthreads();
    if (kt + 1 < NT) stage(cur ^ 1, (kt + 1) * 32);
    f16x8 af[4], bf[4];
#pragma unroll
    for (int m = 0; m < 4; ++m)
      af[m] = *(const f16x8*)&As[cur][(wr * 64 + m * 16 + lr) * 32 + lg * 8];
#pragma unroll
    for (int n = 0; n < 4; ++n)
      bf[n] = *(const f16x8*)&Bs[cur][(wc * 64 + n * 16 + lr) * 32 + lg * 8];
#pragma unroll
    for (int m = 0; m < 4; ++m)
#pragma unroll
      for (int n = 0; n < 4; ++n) acc[m][n] = mfma16(af[m], bf[n], acc[m][n]);
    cur ^= 1;
  }

  const int sec = n0 >> 10;  // 0=q 1=k 2=v (block-uniform)
#pragma unroll
  for (int m = 0; m < 4; ++m) {
#pragma unroll
    for (int n = 0; n < 4; ++n) {
      const int col = n0 + wc * 64 + n * 16 + lr;
      const int cc = col & 1023;
      const int h = cc >> 6, r = cc & 63;
      const float bv = bias[h * 192 + sec * 64 + r];
      const int row0 = m0 + wr * 64 + m * 16 + lg * 4;
      const int b = row0 >> 11, s0 = row0 & (SEQ - 1);
      if (sec == 2) {  // V^T: i -> s consecutive, 4-aligned -> one 8B store
        f16x4 vv;
#pragma unroll
        for (int i = 0; i < 4; ++i) vv[i] = (_Float16)(acc[m][n][i] + bv);
        *(f16x4*)&ov[(((size_t)b * NH + h) * HD_ + r) * SEQ + s0] = vv;
      } else {
#pragma unroll
        for (int i = 0; i < 4; ++i) {
          const float v = acc[m][n][i] + bv;
          const size_t dst = (((size_t)b * NH + h) * SEQ + s0 + i) * HD_ + r;
          if (sec == 0)
            oq[dst] = (_Float16)(v * 11.5415603f);  // 8*log2(e) folded
          else
            ok[dst] = (_Float16)v;
        }
      }
    }
  }
}

// ---------------- proj GEMM: a_o f16 x Wproj_t f16^T -> f32 + bias ----------------
__global__ __launch_bounds__(256) void k_gemm_proj(const _Float16* __restrict__ A,
                                                   const _Float16* __restrict__ Bt,
                                                   const float* __restrict__ bias,
                                                   float* __restrict__ of) {
  constexpr int K = EMB, N = EMB;
  __shared__ _Float16 As[2][128 * 32];
  __shared__ _Float16 Bs[2][128 * 32];
  const int t = threadIdx.x;
  const int l = t & 63, w = t >> 6;
  const int lr = l & 15, lg = l >> 4;
  const int wr = w >> 1, wc = w & 1;
  const int m0 = blockIdx.y * 128, n0 = blockIdx.x * 128;

  auto stage = [&](int buf, int k0) {
#pragma unroll
    for (int j = 0; j < 2; ++j) {
      const int c = t + 256 * j;
      const int row = c >> 2, cb = c & 3;
      gload_lds16(A + (size_t)(m0 + row) * K + k0 + cb * 8, &As[buf][c * 8]);
      gload_lds16(Bt + (size_t)(n0 + row) * K + k0 + cb * 8, &Bs[buf][c * 8]);
    }
  };

  f32x4 acc[4][4];
#pragma unroll
  for (int m = 0; m < 4; ++m)
#pragma unroll
    for (int n = 0; n < 4; ++n) acc[m][n] = f32x4{0.f, 0.f, 0.f, 0.f};

  stage(0, 0);
  const int NT = K / 32;
  int cur = 0;
  for (int kt = 0; kt < NT; ++kt) {
    __syncthreads();
    if (kt + 1 < NT) stage(cur ^ 1, (kt + 1) * 32);
    f16x8 af[4], bf[4];
#pragma unroll
    for (int m = 0; m < 4; ++m)
      af[m] = *(const f16x8*)&As[cur][(wr * 64 + m * 16 + lr) * 32 + lg * 8];
#pragma unroll
    for (int n = 0; n < 4; ++n)
      bf[n] = *(const f16x8*)&Bs[cur][(wc * 64 + n * 16 + lr) * 32 + lg * 8];
#pragma unroll
    for (int m = 0; m < 4; ++m)
#pragma unroll
      for (int n = 0; n < 4; ++n) acc[m][n] = mfma16(af[m], bf[n], acc[m][n]);
    cur ^= 1;
  }

#pragma unroll
  for (int m = 0; m < 4; ++m)
#pragma unroll
    for (int n = 0; n < 4; ++n)
#pragma unroll
      for (int i = 0; i < 4; ++i) {
        const int row = m0 + wr * 64 + m * 16 + lg * 4 + i;
        const int col = n0 + wc * 64 + n * 16 + lr;
        of[(size_t)row * N + col] = acc[m][n][i] + bias[col];
      }
}

// ---------------- flash attention, KV-split (R10 proven body, 77.8us) ----------------
// grid 1024: (bh, 128 q-rows, kv-half). Emits unnormalized partial O (f16) +
// per-row (m, lsum). 48KB LDS; T21 swizzle; defer-max THR=8 (base-2).
__global__ __launch_bounds__(512) void k_attn(
    const _Float16* __restrict__ qs, const _Float16* __restrict__ ks,
    const _Float16* __restrict__ vt, _Float16* __restrict__ op,
    float* __restrict__ marr, float* __restrict__ larr) {
  __shared__ _Float16 Kt[2][64][64];   // [buf][kv][d]   swizzled rows (128B)
  __shared__ _Float16 Vt[2][64][64];   // [buf][d][kv]   swizzled rows
  __shared__ _Float16 Pl[8][16][64];   // per-wave P [q][kv], swizzled rows
  const int t = threadIdx.x;
  const int l = t & 63, w = t >> 6;          // w in [0,8)
  const int lr = l & 15, lg = l >> 4;
  // XCD-grouping: id&7 -> XCD; per XCD: 4 heads x 16 q-blocks x 2 halves
  const int id = blockIdx.x;
  const int xc = id & 7, m_ = id >> 3;       // m_ in [0,128)
  const int kvh = m_ & 1;
  const int bh = xc + 8 * (m_ >> 5);
  const int qb = ((m_ >> 1) & 15) * 128 + w * 16;
  const int kvbase = kvh * (SEQ / 2);

  // Q fragments (B-operand: n=q=lr, k=d)
  const size_t qoff = ((size_t)bh * SEQ + qb + lr) * HD_;
  const f16x8 qf0 = *(const f16x8*)(qs + qoff + lg * 8);
  const f16x8 qf1 = *(const f16x8*)(qs + qoff + 32 + lg * 8);

  const _Float16* kbase = ks + (size_t)bh * SEQ * HD_;
  const _Float16* vbase = vt + (size_t)bh * HD_ * SEQ;

  // async staging: 512 threads cover the 64x64 tile in one pass each for K,V.
  // LDS dest linear (DMA rule); global SOURCE block pre-swizzled (T21).
  const int srow = t >> 3, scb = t & 7;      // srow in [0,64)
  auto stage = [&](const int buf, const int kv0) {
    gload_lds16(kbase + (size_t)(kv0 + srow) * HD_ + (scb ^ (srow & 7)) * 8,
                &Kt[buf][srow][scb * 8]);
    gload_lds16(vbase + (size_t)srow * SEQ + kv0 + (scb ^ (srow & 7)) * 8,
                &Vt[buf][srow][scb * 8]);
  };

  stage(0, kvbase);

  float mr = -1e30f, lsum = 0.f;
  f32x4 oacc[4];
#pragma unroll
  for (int n = 0; n < 4; ++n) oacc[n] = f32x4{0.f, 0.f, 0.f, 0.f};

  const int NT = SEQ / 128;  // 16 tiles per half
  for (int it = 0; it < NT; ++it) {
    const int cur = it & 1;
    __syncthreads();  // drains vmcnt: buf[cur] DMA complete; prev reads done
    if (it + 1 < NT) stage(cur ^ 1, kvbase + (it + 1) * 64);

    // S^T = K Q^T : lane holds S[kv=16*t4+4*lg+i][q=lr]   (base-2 logits)
    f32x4 sa[4];
    __builtin_amdgcn_s_setprio(1);
#pragma unroll
    for (int t4 = 0; t4 < 4; ++t4) {
      const int r = t4 * 16 + lr;
      const f16x8 kf0 = swzread(&Kt[cur][0][0], r, lg);
      const f16x8 kf1 = swzread(&Kt[cur][0][0], r, lg + 4);
      f32x4 s = mfma16(kf0, qf0, f32x4{0.f, 0.f, 0.f, 0.f});
      sa[t4] = mfma16(kf1, qf1, s);
    }
    __builtin_amdgcn_s_setprio(0);

    // online softmax (per-lane q-row), defer-max with THR=8 (base-2)
    float t01 = fmaxf(fmaxf(sa[0][0], sa[0][1]), fmaxf(sa[0][2], sa[0][3]));
    float t23 = fmaxf(fmaxf(sa[1][0], sa[1][1]), fmaxf(sa[1][2], sa[1][3]));
    float t45 = fmaxf(fmaxf(sa[2][0], sa[2][1]), fmaxf(sa[2][2], sa[2][3]));
    float t67 = fmaxf(fmaxf(sa[3][0], sa[3][1]), fmaxf(sa[3][2], sa[3][3]));
    float tm = fmaxf(fmaxf(t01, t23), fmaxf(t45, t67));
    tm = fmaxf(tm, __shfl_xor(tm, 16));
    tm = fmaxf(tm, __shfl_xor(tm, 32));

    if (__any(tm > mr + 8.0f)) {  // wave-uniform rescale
      const float nm = fmaxf(mr, tm);
      const float corr = exp2f(mr - nm);
      mr = nm;
      lsum *= corr;
      float cb4[4];
#pragma unroll
      for (int i = 0; i < 4; ++i)
        cb4[i] = __shfl(corr, (l & 48) + ((l >> 4) << 2) + i);
#pragma unroll
      for (int n = 0; n < 4; ++n)
#pragma unroll
        for (int i = 0; i < 4; ++i) oacc[n][i] *= cb4[i];
    }

    float ts = 0.f;
    char* plbase = (char*)&Pl[w][0][0];
#pragma unroll
    for (int t4 = 0; t4 < 4; ++t4) {
      f16x4 pp;
#pragma unroll
      for (int i = 0; i < 4; ++i) {
        const float p = exp2f(sa[t4][i] - mr);
        ts += p;
        pp[i] = (_Float16)p;
      }
      // P[q=lr][kv=t4*16+lg*4+i], swizzled row (XOR bits 4-6, 8B aligned)
      *(f16x4*)(plbase + lr * 128 + ((t4 * 32 + lg * 8) ^ ((lr & 7) << 4))) = pp;
    }
    ts += __shfl_xor(ts, 16);
    ts += __shfl_xor(ts, 32);
    lsum += ts;

    // O += P V (A=P[q][kv], B=V^T[d][kv])
    const f16x8 aP0 = swzread(&Pl[w][0][0], lr, lg);
    const f16x8 aP1 = swzread(&Pl[w][0][0], lr, lg + 4);
    __builtin_amdgcn_s_setprio(1);
#pragma unroll
    for (int n = 0; n < 4; ++n) {
      const int d = n * 16 + lr;
      const f16x8 bv0 = swzread(&Vt[cur][0][0], d, lg);
      const f16x8 bv1 = swzread(&Vt[cur][0][0], d, lg + 4);
      oacc[n] = mfma16(aP0, bv0, oacc[n]);
      oacc[n] = mfma16(aP1, bv1, oacc[n]);
    }
    __builtin_amdgcn_s_setprio(0);
  }

  // epilogue: write per-row (m, lsum) — lanes 0-15 hold rows lr=l
  const size_t mlbase = ((size_t)kvh * 32 + bh) * SEQ + qb;
  if (l < 16) {
    marr[mlbase + l] = mr;
    larr[mlbase + l] = lsum;
  }
  // store unnormalized partial O as f16
  _Float16* opb = op + (size_t)kvh * BATCH * SEQ * EMB;
  const int b = bh >> 4, h = bh & 15;
#pragma unroll
  for (int n = 0; n < 4; ++n)
#pragma unroll
    for (int i = 0; i < 4; ++i) {
      const int row = qb + ((l >> 4) << 2) + i;
      opb[((size_t)b * SEQ + row) * EMB + h * HD_ + n * 16 + lr] =
          (_Float16)oacc[n][i];
    }
}

// ---------------- combine the two KV-halves ----------------
__global__ __launch_bounds__(256) void k_combine(const _Float16* __restrict__ op,
                                                 const float* __restrict__ marr,
                                                 const float* __restrict__ larr,
                                                 _Float16* __restrict__ ao) {
  const int idx = blockIdx.x * 256 + threadIdx.x;  // [0, B*S*E/8)
  const int e8 = idx & 127;                        // EMB/8 = 128
  const size_t rs = (size_t)(idx >> 7);            // b*SEQ + s
  const int h = e8 >> 3;
  const int b = (int)(rs >> 11);
  const size_t s = rs & (SEQ - 1);
  const size_t mi = ((size_t)b * NH + h) * SEQ + s;
  const float m1 = marr[mi], l1 = larr[mi];
  const float m2 = marr[(size_t)32 * SEQ + mi], l2 = larr[(size_t)32 * SEQ + mi];
  const float mx = fmaxf(m1, m2);
  const float w1 = exp2f(m1 - mx), w2 = exp2f(m2 - mx);
  const float inv = 1.0f / (l1 * w1 + l2 * w2);
  const f16x8 o1 = ((const f16x8*)op)[idx];
  const f16x8 o2 = ((const f16x8*)op)[idx + (BATCH * SEQ * EMB / 8)];
  f16x8 r;
#pragma unroll
  for (int j = 0; j < 8; ++j)
    r[j] = (_Float16)(((float)o1[j] * w1 + (float)o2[j] * w2) * inv);
  ((f16x8*)ao)[idx] = r;
}

extern "C" void kernel_launch(void* const* d_in, const int* in_sizes, int n_in,
                              void* d_out, int out_size, void* d_ws, size_t ws_size,
                              hipStream_t stream) {
  const float* query = (const float*)d_in[0];
  const float* Wqkv = (const float*)d_in[3];
  const float* bqkv = (const float*)d_in[4];
  const float* Wproj = (const float*)d_in[5];
  const float* bproj = (const float*)d_in[6];
  float* out = (float*)d_out;

  char* ws = (char*)d_ws;
  const size_t MB = 1024 * 1024;
  _Float16* q_f16   = (_Float16*)(ws + 0);         // 8MB; dead after QKV GEMM
  _Float16* Wqkv_t  = (_Float16*)(ws + 16 * MB);   // 6MB f16 (rows: q|k|v)
  _Float16* q_s     = (_Float16*)(ws + 24 * MB);   // 8MB [32][2048][64]
  _Float16* k_s     = (_Float16*)(ws + 32 * MB);   // 8MB
  _Float16* v_t     = (_Float16*)(ws + 40 * MB);   // 8MB [32][64][2048]
  _Float16* op      = (_Float16*)(ws + 0);         // 16MB partials (alias q_f16 + spare)
  _Float16* Wproj_t = (_Float16*)(ws + 48 * MB);   // 2MB
  float*    marr    = (float*)(ws + 50 * MB);      // 512KB [2][32][2048]
  float*    larr    = (float*)(ws + 50 * MB + 512 * 1024);  // 512KB
  _Float16* a_o     = (_Float16*)(ws + 51 * MB);   // 8MB

  const int M = BATCH * SEQ;  // 4096
  k_convert<<<(M * EMB / 4 + 255) / 256, 256, 0, stream>>>(query, q_f16, M * EMB / 4);
  k_transpose<1><<<dim3(3 * EMB / 32, EMB / 32), 256, 0, stream>>>(Wqkv, Wqkv_t, EMB,
                                                                   3 * EMB);
  k_gemm_qkv<<<dim3(24, M / 128), 256, 0, stream>>>(q_f16, Wqkv_t, bqkv, q_s, k_s, v_t);
  k_transpose<0><<<dim3(EMB / 32, EMB / 32), 256, 0, stream>>>(Wproj, Wproj_t, EMB, EMB);
  k_attn<<<dim3(1024), 512, 0, stream>>>(q_s, k_s, v_t, op, marr, larr);
  k_combine<<<dim3(BATCH * SEQ * EMB / 8 / 256), 256, 0, stream>>>(op, marr, larr, a_o);
  k_gemm_proj<<<dim3(EMB / 128, M / 128), 256, 0, stream>>>(a_o, Wproj_t, bproj, out);
}